// Round 5
// baseline (1351.249 us; speedup 1.0000x reference)
//
#include <hip/hip_runtime.h>

// RelationalDelayGNNStage: N=20000, E=500000, D=256, T=4, NTYPES=3
// Round 5: latency attacks. (1) aggregate: 4x edge unroll (independent gathers).
// (2) GEMM: single-wave blocks (TM=32,TN=64, grid 2500) -> barriers are wave-
// private no-ops, 9.8 independent waves/CU. (3) shuffle-based scan.
// Numerics: plain f16 operands (A scale 2^-6, W scale 2^4), fp32 accum; measured
// absmax stuck at fp32 floor (32.0 of 174 budget) since round 2.

#define NN 20000
#define NE 500000
#define DD 256
#define TT 4
#define NT 3
#define BK 32

typedef _Float16 f16;
typedef _Float16 f16x8 __attribute__((ext_vector_type(8)));
typedef _Float16 f16x4v __attribute__((ext_vector_type(4)));
typedef float f32x4 __attribute__((ext_vector_type(4)));

typedef const __attribute__((address_space(1))) void* gptr_t;
typedef __attribute__((address_space(3))) void* lptr_t;

__device__ __forceinline__ void gll16(const void* g, void* l) {
  __builtin_amdgcn_global_load_lds((gptr_t)g, (lptr_t)l, 16, 0, 0);
}

__device__ inline void f4add(float4& a, const float4 b) {
  a.x += b.x; a.y += b.y; a.z += b.z; a.w += b.w;
}

// ---------------- CSR build ----------------

__global__ void k_hist(const int* __restrict__ ei, const int* __restrict__ ea,
                       int* __restrict__ deg, int* __restrict__ cnt) {
  int e = blockIdx.x * 256 + threadIdx.x;
  if (e >= NE) return;
  int dst = ei[NE + e];
  atomicAdd(&deg[dst], 1);
  int hop = ea[2 * e];
  int et  = ea[2 * e + 1];
  atomicAdd(&cnt[et * NN + dst], 1);
  if (hop >= 2) atomicAdd(&cnt[(3 + hop - 2) * NN + dst], 1);
}

__global__ void k_scan(const int* __restrict__ deg, int* __restrict__ row_ptr,
                       int* __restrict__ cursor) {
  __shared__ int wsum[16];
  __shared__ int s_run;
  int tid = threadIdx.x, lane = tid & 63, wv = tid >> 6;
  if (tid == 0) s_run = 0;
  __syncthreads();
  for (int base = 0; base < NN; base += 1024) {
    int i = base + tid;
    int v = (i < NN) ? deg[i] : 0;
    int s = v;
#pragma unroll
    for (int off = 1; off < 64; off <<= 1) {
      int t = __shfl_up(s, off, 64);
      if (lane >= off) s += t;
    }
    if (lane == 63) wsum[wv] = s;
    __syncthreads();
    if (wv == 0) {
      int ws = (lane < 16) ? wsum[lane] : 0;
#pragma unroll
      for (int off = 1; off < 16; off <<= 1) {
        int t = __shfl_up(ws, off, 64);
        if (lane >= off) ws += t;
      }
      if (lane < 16) wsum[lane] = ws;
    }
    __syncthreads();
    int wave_excl = (wv == 0) ? 0 : wsum[wv - 1];
    int excl = s_run + wave_excl + s - v;
    if (i < NN) { row_ptr[i] = excl; cursor[i] = excl; }
    __syncthreads();
    if (tid == 0) s_run += wsum[15];
    __syncthreads();
  }
  if (tid == 0) row_ptr[NN] = s_run;
}

__global__ void k_scatter(const int* __restrict__ ei, const int* __restrict__ ea,
                          int* __restrict__ cursor, int* __restrict__ records) {
  int e = blockIdx.x * 256 + threadIdx.x;
  if (e >= NE) return;
  int src = ei[e];
  int dst = ei[NE + e];
  int hop = ea[2 * e];
  int et  = ea[2 * e + 1];
  int pos = atomicAdd(&cursor[dst], 1);
  records[pos] = src | ((hop - 1) << 18) | (et << 20);
}

// ---------------- W: fp32 -> transposed f16, scale 2^4 ----------------

__global__ void k_wsplit(const float* __restrict__ W_edge, const float* __restrict__ W_hop,
                         f16* __restrict__ Wout) {
  int w = blockIdx.y;
  int flat = blockIdx.x * 256 + threadIdx.x;  // 0..65535
  int k = flat & 255, n = flat >> 8;
  const float* src = (w < 12) ? (W_edge + (size_t)w * 65536)
                              : (W_hop + (size_t)(w - 12) * 65536);
  Wout[(size_t)w * 65536 + n * 256 + k] = (f16)(src[k * 256 + n] * 16.0f);
}

// ---------------- x fp32 -> f16 copy ----------------

__global__ void k_xcast(const float* __restrict__ x, f16* __restrict__ xh) {
  size_t i = (size_t)(blockIdx.x * 256 + threadIdx.x) * 4;
  float4 v = *(const float4*)(x + i);
  f16x4v h = { (f16)v.x, (f16)v.y, (f16)v.z, (f16)v.w };
  *(f16x4v*)(xh + i) = h;
}

// ---------------- aggregation: one wave per node, 4x-unrolled f16 gather ----------------

__device__ inline void store_h(f16* __restrict__ p, float4 v) {
  const float s = 0.015625f;  // 2^-6
  f16x4v h = { (f16)(v.x * s), (f16)(v.y * s), (f16)(v.z * s), (f16)(v.w * s) };
  *(f16x4v*)p = h;
}

__device__ __forceinline__ void acc_rec(int rec, f16x4v hv,
    float4& a0, float4& a1, float4& a2, float4& c2, float4& c3, float4& c4) {
  float4 xv = make_float4((float)hv.x, (float)hv.y, (float)hv.z, (float)hv.w);
  int hopm2 = ((rec >> 18) & 3) - 1;
  int et    = (rec >> 20) & 3;
  if (et == 0)      f4add(a0, xv);
  else if (et == 1) f4add(a1, xv);
  else              f4add(a2, xv);
  if (hopm2 == 0)      f4add(c2, xv);
  else if (hopm2 == 1) f4add(c3, xv);
  else if (hopm2 == 2) f4add(c4, xv);
}

__global__ __launch_bounds__(256) void k_aggregate(
    const f16* __restrict__ xh,
    const int* __restrict__ row_ptr,
    const int* __restrict__ records,
    f16* __restrict__ e0, f16* __restrict__ e1, f16* __restrict__ e2,
    f16* __restrict__ c2p, f16* __restrict__ c3p, f16* __restrict__ c4p)
{
  int wave = threadIdx.x >> 6;
  int lane = threadIdx.x & 63;
  int v = blockIdx.x * 4 + wave;
  if (v >= NN) return;
  int beg = row_ptr[v], end = row_ptr[v + 1];
  float4 a0 = make_float4(0, 0, 0, 0), a1 = a0, a2 = a0;
  float4 c2 = a0, c3 = a0, c4 = a0;
  const f16* xb = xh + (lane << 2);
  int e = beg;
  for (; e + 4 <= end; e += 4) {
    int r0 = __builtin_amdgcn_readfirstlane(records[e]);
    int r1 = __builtin_amdgcn_readfirstlane(records[e + 1]);
    int r2 = __builtin_amdgcn_readfirstlane(records[e + 2]);
    int r3 = __builtin_amdgcn_readfirstlane(records[e + 3]);
    f16x4v h0 = *(const f16x4v*)(xb + (size_t)(r0 & 0x3FFFF) * DD);
    f16x4v h1 = *(const f16x4v*)(xb + (size_t)(r1 & 0x3FFFF) * DD);
    f16x4v h2 = *(const f16x4v*)(xb + (size_t)(r2 & 0x3FFFF) * DD);
    f16x4v h3 = *(const f16x4v*)(xb + (size_t)(r3 & 0x3FFFF) * DD);
    acc_rec(r0, h0, a0, a1, a2, c2, c3, c4);
    acc_rec(r1, h1, a0, a1, a2, c2, c3, c4);
    acc_rec(r2, h2, a0, a1, a2, c2, c3, c4);
    acc_rec(r3, h3, a0, a1, a2, c2, c3, c4);
  }
  for (; e < end; ++e) {
    int r0 = __builtin_amdgcn_readfirstlane(records[e]);
    f16x4v h0 = *(const f16x4v*)(xb + (size_t)(r0 & 0x3FFFF) * DD);
    acc_rec(r0, h0, a0, a1, a2, c2, c3, c4);
  }
  size_t o = (size_t)v * DD + (lane << 2);
  store_h(e0 + o, a0);
  store_h(e1 + o, a1);
  store_h(e2 + o, a2);
  if (c2p) store_h(c2p + o, c2);
  if (c3p) store_h(c3p + o, c3);
  if (c4p) store_h(c4p + o, c4);
}

// ---------------- f16 MFMA GEMM: single-wave blocks ----------------
// Tile 32(M) x 64(N), BK=32, 64 threads (1 wave). Grid (625, 4) = 2500 blocks.
// Barriers are wave-private (1-wave group) -> waves fully decoupled.
// LDS swizzle: slot (row r, chunk q) holds global 16B chunk  q ^ ((r>>1)&3).

struct GemmArgs {
  const f16* A[6];     // aggregates, scale 2^-6
  const f16* W[6];     // transposed, scale 2^4
  const float* bias[6];
  const int*   cnt[6];
  int nch;
  const float* x_in;
  float*       x_out;
  f16*         xh_out;
};

__global__ __launch_bounds__(64) void k_gemm(GemmArgs args) {
  __shared__ __align__(16) f16 sA[32 * BK];    // 2 KB
  __shared__ __align__(16) f16 sB[64 * BK];    // 4 KB
  const int lane = threadIdx.x;
  const int m0 = blockIdx.x * 32;     // 625*32 = 20000 exact
  const int n0 = blockIdx.y * 64;
  const int nch = args.nch;

  f32x4 acc[2][4];
#pragma unroll
  for (int i = 0; i < 2; i++)
#pragma unroll
    for (int j = 0; j < 4; j++) acc[i][j] = (f32x4){0.f, 0.f, 0.f, 0.f};

  // staging: LDS slot s (16B) <- tile row r=s>>2, global chunk u = (s&3)^((r>>1)&3)
  // A: 2 instrs (slots lane, 64+lane); B: 4 instrs (slots i*64+lane)
  int aoff[2], boff[4];
#pragma unroll
  for (int i = 0; i < 2; i++) {
    int s = i * 64 + lane;
    int r = s >> 2, u = (s & 3) ^ ((r >> 1) & 3);
    aoff[i] = r * 512 + u * 16;
  }
#pragma unroll
  for (int i = 0; i < 4; i++) {
    int s = i * 64 + lane;
    int r = s >> 2, u = (s & 3) ^ ((r >> 1) & 3);
    boff[i] = r * 512 + u * 16;
  }
  char* dA = (char*)sA + lane * 16;
  char* dB = (char*)sB + lane * 16;

  // fragment read offsets (f16 units), un-swizzling
  const int fr = lane & 15;
  const int gq = lane >> 4;
  int offA[2], offB[4];
#pragma unroll
  for (int mi = 0; mi < 2; mi++) {
    int rr = mi * 16 + fr;
    offA[mi] = rr * BK + ((gq ^ ((rr >> 1) & 3)) << 3);
  }
#pragma unroll
  for (int ni = 0; ni < 4; ni++) {
    int rr = ni * 16 + fr;
    offB[ni] = rr * BK + ((gq ^ ((rr >> 1) & 3)) << 3);
  }

  for (int c = 0; c < nch; ++c) {
    const char* pa = (const char*)args.A[c] + (size_t)m0 * 512;
    const char* pb = (const char*)args.W[c] + (size_t)n0 * 512;
#pragma unroll
    for (int kb = 0; kb < 512; kb += 64) {   // 8 K-iters of BK=32
      gll16(pa + aoff[0] + kb, dA);
      gll16(pa + aoff[1] + kb, dA + 1024);
      gll16(pb + boff[0] + kb, dB);
      gll16(pb + boff[1] + kb, dB + 1024);
      gll16(pb + boff[2] + kb, dB + 2048);
      gll16(pb + boff[3] + kb, dB + 3072);
      __syncthreads();   // 1-wave group: waitcnt only, barrier is a no-op
      f16x8 fA[2], fB[4];
#pragma unroll
      for (int mi = 0; mi < 2; mi++) fA[mi] = *(const f16x8*)&sA[offA[mi]];
#pragma unroll
      for (int ni = 0; ni < 4; ni++) fB[ni] = *(const f16x8*)&sB[offB[ni]];
#pragma unroll
      for (int mi = 0; mi < 2; mi++)
#pragma unroll
        for (int ni = 0; ni < 4; ni++)
          acc[mi][ni] = __builtin_amdgcn_mfma_f32_16x16x32_f16(fA[mi], fB[ni], acc[mi][ni], 0, 0, 0);
      __syncthreads();
    }
  }

  // epilogue: out = x + relu(acc*4 + sum_c cnt_c[row]*b_c[col]);  4 = 2^6 * 2^-4
  float bcol[4][6];
#pragma unroll
  for (int ni = 0; ni < 4; ni++) {
    int gcol = n0 + ni * 16 + fr;
#pragma unroll
    for (int c = 0; c < 6; c++)
      bcol[ni][c] = (c < nch) ? args.bias[c][gcol] : 0.f;
  }
  const int rowq = (lane >> 4) * 4;
#pragma unroll
  for (int mi = 0; mi < 2; mi++) {
#pragma unroll
    for (int rI = 0; rI < 4; rI++) {
      int grow = m0 + mi * 16 + rowq + rI;
      float cv[6];
#pragma unroll
      for (int c = 0; c < 6; c++)
        cv[c] = (c < nch) ? (float)args.cnt[c][grow] : 0.f;
      size_t rowoff = (size_t)grow * DD;
#pragma unroll
      for (int ni = 0; ni < 4; ni++) {
        int gcol = n0 + ni * 16 + fr;
        float v = acc[mi][ni][rI] * 4.0f;
#pragma unroll
        for (int c = 0; c < 6; c++) v += cv[c] * bcol[ni][c];
        float outv = args.x_in[rowoff + gcol] + fmaxf(v, 0.f);
        args.x_out[rowoff + gcol] = outv;
        args.xh_out[rowoff + gcol] = (f16)outv;
      }
    }
  }
}

// ---------------- host ----------------

extern "C" void kernel_launch(void* const* d_in, const int* in_sizes, int n_in,
                              void* d_out, int out_size, void* d_ws, size_t ws_size,
                              hipStream_t stream) {
  const float* x      = (const float*)d_in[0];
  const int* edge_index = (const int*)d_in[1];
  const int* edge_attr  = (const int*)d_in[2];
  const float* W_edge = (const float*)d_in[3];
  const float* b_edge = (const float*)d_in[4];
  const float* W_hop  = (const float*)d_in[5];
  const float* b_hop  = (const float*)d_in[6];
  float* out = (float*)d_out;

  // workspace layout
  char* ws = (char*)d_ws;
  int* deg     = (int*)ws;            // N
  int* cnt     = deg + NN;            // 6N
  int* row_ptr = cnt + 6 * NN;        // N+1
  int* cursor  = row_ptr + (NN + 1);  // N
  int* records = cursor + NN;         // E
  size_t int_count = (size_t)NN + 6 * NN + (NN + 1) + NN + NE;
  const size_t ND = (size_t)NN * DD;
  f16* Wsplit = (f16*)(ws + ((int_count * 4 + 255) & ~(size_t)255));  // 24 * 65536 f16
  f16* xh = Wsplit + (size_t)24 * 65536;                              // N*D f16
  f16* aggBase = xh + ND;
  f16* agg[9];
  for (int i = 0; i < 9; i++) agg[i] = aggBase + (size_t)i * ND;
  f16** Cb = agg + 3;  // Cb[0..5]: C2_s0,C2_s1,C2_s2, C3_s0,C3_s1, C4_s0

  hipMemsetAsync(deg, 0, 7 * NN * sizeof(int), stream);
  hipMemcpyAsync(out, x, ND * sizeof(float), hipMemcpyDeviceToDevice, stream);

  k_hist<<<(NE + 255) / 256, 256, 0, stream>>>(edge_index, edge_attr, deg, cnt);
  k_scan<<<1, 1024, 0, stream>>>(deg, row_ptr, cursor);
  k_scatter<<<(NE + 255) / 256, 256, 0, stream>>>(edge_index, edge_attr, cursor, records);
  k_wsplit<<<dim3(256, 24), 256, 0, stream>>>(W_edge, W_hop, Wsplit);
  k_xcast<<<ND / 1024, 256, 0, stream>>>(x, xh);

  for (int t = 0; t < TT; ++t) {
    f16* c2p = (t <= 2) ? Cb[t]     : nullptr;
    f16* c3p = (t <= 1) ? Cb[3 + t] : nullptr;
    f16* c4p = (t == 0) ? Cb[5]     : nullptr;
    k_aggregate<<<NN / 4, 256, 0, stream>>>(xh, row_ptr, records,
                                            agg[0], agg[1], agg[2], c2p, c3p, c4p);

    GemmArgs ga{};
    for (int e = 0; e < NT; ++e) {
      ga.A[e]    = agg[e];
      ga.W[e]    = Wsplit + (size_t)(t * NT + e) * 65536;
      ga.bias[e] = b_edge + (size_t)(t * NT + e) * DD;
      ga.cnt[e]  = cnt + (size_t)e * NN;
    }
    int nc = NT;
    for (int k = 2; k <= t + 1; ++k) {
      int s = t + 1 - k;
      ga.A[nc]    = (k == 2) ? Cb[s] : (k == 3) ? Cb[3 + s] : Cb[5];
      ga.W[nc]    = Wsplit + (size_t)(12 + t * 3 + (k - 2)) * 65536;
      ga.bias[nc] = b_hop + (size_t)(t * (TT - 1) + (k - 2)) * DD;
      ga.cnt[nc]  = cnt + (size_t)(3 + (k - 2)) * NN;
      nc++;
    }
    for (int c = nc; c < 6; ++c) {
      ga.A[c] = ga.A[0]; ga.W[c] = ga.W[0]; ga.bias[c] = ga.bias[0]; ga.cnt[c] = ga.cnt[0];
    }
    ga.nch = nc;
    ga.x_in = out;
    ga.x_out = out;
    ga.xh_out = xh;
    k_gemm<<<dim3(625, 4), 64, 0, stream>>>(ga);
  }
}

// Round 6
// 1055.569 us; speedup vs baseline: 1.2801x; 1.2801x over previous
//
#include <hip/hip_runtime.h>

// RelationalDelayGNNStage: N=20000, E=500000, D=256, T=4, NTYPES=3
// Round 6: un-spill the aggregation. R5's 4x unroll spilled accumulators to
// scratch (WRITE_SIZE 60->855 MB, VGPR=16). Fix: column-split — 2 waves/node,
// each wave owns 128 cols, lane holds 2 cols (f16x2) -> 6 float2 accumulators
// = 12 VGPRs, 4x edge unroll fits in registers. Plus LDS-transpose k_wsplit.
// Numerics: f16 operands (A scale 2^-6, W scale 2^4), fp32 accum; absmax at
// fp32 floor (32.0 of 174) since round 2.

#define NN 20000
#define NE 500000
#define DD 256
#define TT 4
#define NT 3
#define BK 32

typedef _Float16 f16;
typedef _Float16 f16x8 __attribute__((ext_vector_type(8)));
typedef _Float16 f16x4v __attribute__((ext_vector_type(4)));
typedef _Float16 f16x2 __attribute__((ext_vector_type(2)));
typedef float f32x4 __attribute__((ext_vector_type(4)));

typedef const __attribute__((address_space(1))) void* gptr_t;
typedef __attribute__((address_space(3))) void* lptr_t;

__device__ __forceinline__ void gll16(const void* g, void* l) {
  __builtin_amdgcn_global_load_lds((gptr_t)g, (lptr_t)l, 16, 0, 0);
}

// ---------------- CSR build ----------------

__global__ void k_hist(const int* __restrict__ ei, const int* __restrict__ ea,
                       int* __restrict__ deg, int* __restrict__ cnt) {
  int e = blockIdx.x * 256 + threadIdx.x;
  if (e >= NE) return;
  int dst = ei[NE + e];
  atomicAdd(&deg[dst], 1);
  int hop = ea[2 * e];
  int et  = ea[2 * e + 1];
  atomicAdd(&cnt[et * NN + dst], 1);
  if (hop >= 2) atomicAdd(&cnt[(3 + hop - 2) * NN + dst], 1);
}

__global__ void k_scan(const int* __restrict__ deg, int* __restrict__ row_ptr,
                       int* __restrict__ cursor) {
  __shared__ int wsum[16];
  __shared__ int s_run;
  int tid = threadIdx.x, lane = tid & 63, wv = tid >> 6;
  if (tid == 0) s_run = 0;
  __syncthreads();
  for (int base = 0; base < NN; base += 1024) {
    int i = base + tid;
    int v = (i < NN) ? deg[i] : 0;
    int s = v;
#pragma unroll
    for (int off = 1; off < 64; off <<= 1) {
      int t = __shfl_up(s, off, 64);
      if (lane >= off) s += t;
    }
    if (lane == 63) wsum[wv] = s;
    __syncthreads();
    if (wv == 0) {
      int ws = (lane < 16) ? wsum[lane] : 0;
#pragma unroll
      for (int off = 1; off < 16; off <<= 1) {
        int t = __shfl_up(ws, off, 64);
        if (lane >= off) ws += t;
      }
      if (lane < 16) wsum[lane] = ws;
    }
    __syncthreads();
    int wave_excl = (wv == 0) ? 0 : wsum[wv - 1];
    int excl = s_run + wave_excl + s - v;
    if (i < NN) { row_ptr[i] = excl; cursor[i] = excl; }
    __syncthreads();
    if (tid == 0) s_run += wsum[15];
    __syncthreads();
  }
  if (tid == 0) row_ptr[NN] = s_run;
}

__global__ void k_scatter(const int* __restrict__ ei, const int* __restrict__ ea,
                          int* __restrict__ cursor, int* __restrict__ records) {
  int e = blockIdx.x * 256 + threadIdx.x;
  if (e >= NE) return;
  int src = ei[e];
  int dst = ei[NE + e];
  int hop = ea[2 * e];
  int et  = ea[2 * e + 1];
  int pos = atomicAdd(&cursor[dst], 1);
  records[pos] = src | ((hop - 1) << 18) | (et << 20);
}

// ---------------- W: fp32 -> transposed f16 (scale 2^4), LDS-tiled ----------------
// out[w][n*256+k] = in[w][k*256+n] * 16. 64x64 float tile, both sides coalesced.

__global__ __launch_bounds__(256) void k_wsplit(
    const float* __restrict__ W_edge, const float* __restrict__ W_hop,
    f16* __restrict__ Wout) {
  __shared__ float tile[64][65];
  int w = blockIdx.z;
  int tk = blockIdx.x * 64;
  int tn = blockIdx.y * 64;
  const float* src = (w < 12) ? (W_edge + (size_t)w * 65536)
                              : (W_hop + (size_t)(w - 12) * 65536);
  f16* dst = Wout + (size_t)w * 65536;
  int c = threadIdx.x & 63;
  int r0 = threadIdx.x >> 6;
#pragma unroll
  for (int i = 0; i < 16; i++) {
    int r = i * 4 + r0;
    tile[r][c] = src[(size_t)(tk + r) * 256 + tn + c] * 16.0f;
  }
  __syncthreads();
#pragma unroll
  for (int i = 0; i < 16; i++) {
    int r = i * 4 + r0;
    dst[(size_t)(tn + r) * 256 + tk + c] = (f16)tile[c][r];  // banks (c+r)%32: conflict-free
  }
}

// ---------------- x fp32 -> f16 copy ----------------

__global__ void k_xcast(const float* __restrict__ x, f16* __restrict__ xh) {
  size_t i = (size_t)(blockIdx.x * 256 + threadIdx.x) * 4;
  float4 v = *(const float4*)(x + i);
  f16x4v h = { (f16)v.x, (f16)v.y, (f16)v.z, (f16)v.w };
  *(f16x4v*)(xh + i) = h;
}

// ---------------- aggregation: 2 waves/node (column split), 4x edge unroll ----------------

__device__ __forceinline__ void store_h2(f16* __restrict__ p, float ax, float ay) {
  const float s = 0.015625f;  // 2^-6
  f16x2 h = { (f16)(ax * s), (f16)(ay * s) };
  *(f16x2*)p = h;
}

__device__ __forceinline__ void acc2(int rec, f16x2 h,
    float& a0x, float& a0y, float& a1x, float& a1y, float& a2x, float& a2y,
    float& c2x, float& c2y, float& c3x, float& c3y, float& c4x, float& c4y) {
  float fx = (float)h.x, fy = (float)h.y;
  int hopm2 = ((rec >> 18) & 3) - 1;
  int et    = (rec >> 20) & 3;
  if (et == 0)      { a0x += fx; a0y += fy; }
  else if (et == 1) { a1x += fx; a1y += fy; }
  else              { a2x += fx; a2y += fy; }
  if (hopm2 == 0)      { c2x += fx; c2y += fy; }
  else if (hopm2 == 1) { c3x += fx; c3y += fy; }
  else if (hopm2 == 2) { c4x += fx; c4y += fy; }
}

__global__ __launch_bounds__(256, 4) void k_aggregate(
    const f16* __restrict__ xh,
    const int* __restrict__ row_ptr,
    const int* __restrict__ records,
    f16* __restrict__ e0, f16* __restrict__ e1, f16* __restrict__ e2,
    f16* __restrict__ c2p, f16* __restrict__ c3p, f16* __restrict__ c4p)
{
  int wave = threadIdx.x >> 6;
  int lane = threadIdx.x & 63;
  int v = blockIdx.x * 2 + (wave >> 1);     // node
  int w = wave & 1;                          // column half
  int beg = row_ptr[v], end = row_ptr[v + 1];
  float a0x = 0, a0y = 0, a1x = 0, a1y = 0, a2x = 0, a2y = 0;
  float c2x = 0, c2y = 0, c3x = 0, c3y = 0, c4x = 0, c4y = 0;
  const f16* xb = xh + w * 128 + lane * 2;
  int e = beg;
  for (; e + 4 <= end; e += 4) {
    int r0 = records[e];
    int r1 = records[e + 1];
    int r2 = records[e + 2];
    int r3 = records[e + 3];
    f16x2 h0 = *(const f16x2*)(xb + (size_t)(r0 & 0x3FFFF) * DD);
    f16x2 h1 = *(const f16x2*)(xb + (size_t)(r1 & 0x3FFFF) * DD);
    f16x2 h2 = *(const f16x2*)(xb + (size_t)(r2 & 0x3FFFF) * DD);
    f16x2 h3 = *(const f16x2*)(xb + (size_t)(r3 & 0x3FFFF) * DD);
    acc2(r0, h0, a0x,a0y,a1x,a1y,a2x,a2y,c2x,c2y,c3x,c3y,c4x,c4y);
    acc2(r1, h1, a0x,a0y,a1x,a1y,a2x,a2y,c2x,c2y,c3x,c3y,c4x,c4y);
    acc2(r2, h2, a0x,a0y,a1x,a1y,a2x,a2y,c2x,c2y,c3x,c3y,c4x,c4y);
    acc2(r3, h3, a0x,a0y,a1x,a1y,a2x,a2y,c2x,c2y,c3x,c3y,c4x,c4y);
  }
  for (; e < end; ++e) {
    int r0 = records[e];
    f16x2 h0 = *(const f16x2*)(xb + (size_t)(r0 & 0x3FFFF) * DD);
    acc2(r0, h0, a0x,a0y,a1x,a1y,a2x,a2y,c2x,c2y,c3x,c3y,c4x,c4y);
  }
  size_t o = (size_t)v * DD + w * 128 + lane * 2;
  store_h2(e0 + o, a0x, a0y);
  store_h2(e1 + o, a1x, a1y);
  store_h2(e2 + o, a2x, a2y);
  if (c2p) store_h2(c2p + o, c2x, c2y);
  if (c3p) store_h2(c3p + o, c3x, c3y);
  if (c4p) store_h2(c4p + o, c4x, c4y);
}

// ---------------- f16 MFMA GEMM: single-wave blocks ----------------
// Tile 32(M) x 64(N), BK=32, 64 threads (1 wave). Grid (625, 4) = 2500 blocks.
// LDS swizzle: slot (row r, chunk q) holds global 16B chunk  q ^ ((r>>1)&3).

struct GemmArgs {
  const f16* A[6];     // aggregates, scale 2^-6
  const f16* W[6];     // transposed, scale 2^4
  const float* bias[6];
  const int*   cnt[6];
  int nch;
  const float* x_in;
  float*       x_out;
  f16*         xh_out;
};

__global__ __launch_bounds__(64) void k_gemm(GemmArgs args) {
  __shared__ __align__(16) f16 sA[32 * BK];    // 2 KB
  __shared__ __align__(16) f16 sB[64 * BK];    // 4 KB
  const int lane = threadIdx.x;
  const int m0 = blockIdx.x * 32;     // 625*32 = 20000 exact
  const int n0 = blockIdx.y * 64;
  const int nch = args.nch;

  f32x4 acc[2][4];
#pragma unroll
  for (int i = 0; i < 2; i++)
#pragma unroll
    for (int j = 0; j < 4; j++) acc[i][j] = (f32x4){0.f, 0.f, 0.f, 0.f};

  int aoff[2], boff[4];
#pragma unroll
  for (int i = 0; i < 2; i++) {
    int s = i * 64 + lane;
    int r = s >> 2, u = (s & 3) ^ ((r >> 1) & 3);
    aoff[i] = r * 512 + u * 16;
  }
#pragma unroll
  for (int i = 0; i < 4; i++) {
    int s = i * 64 + lane;
    int r = s >> 2, u = (s & 3) ^ ((r >> 1) & 3);
    boff[i] = r * 512 + u * 16;
  }
  char* dA = (char*)sA + lane * 16;
  char* dB = (char*)sB + lane * 16;

  const int fr = lane & 15;
  const int gq = lane >> 4;
  int offA[2], offB[4];
#pragma unroll
  for (int mi = 0; mi < 2; mi++) {
    int rr = mi * 16 + fr;
    offA[mi] = rr * BK + ((gq ^ ((rr >> 1) & 3)) << 3);
  }
#pragma unroll
  for (int ni = 0; ni < 4; ni++) {
    int rr = ni * 16 + fr;
    offB[ni] = rr * BK + ((gq ^ ((rr >> 1) & 3)) << 3);
  }

  for (int c = 0; c < nch; ++c) {
    const char* pa = (const char*)args.A[c] + (size_t)m0 * 512;
    const char* pb = (const char*)args.W[c] + (size_t)n0 * 512;
#pragma unroll
    for (int kb = 0; kb < 512; kb += 64) {   // 8 K-iters of BK=32
      gll16(pa + aoff[0] + kb, dA);
      gll16(pa + aoff[1] + kb, dA + 1024);
      gll16(pb + boff[0] + kb, dB);
      gll16(pb + boff[1] + kb, dB + 1024);
      gll16(pb + boff[2] + kb, dB + 2048);
      gll16(pb + boff[3] + kb, dB + 3072);
      __syncthreads();   // 1-wave group: waitcnt only
      f16x8 fA[2], fB[4];
#pragma unroll
      for (int mi = 0; mi < 2; mi++) fA[mi] = *(const f16x8*)&sA[offA[mi]];
#pragma unroll
      for (int ni = 0; ni < 4; ni++) fB[ni] = *(const f16x8*)&sB[offB[ni]];
#pragma unroll
      for (int mi = 0; mi < 2; mi++)
#pragma unroll
        for (int ni = 0; ni < 4; ni++)
          acc[mi][ni] = __builtin_amdgcn_mfma_f32_16x16x32_f16(fA[mi], fB[ni], acc[mi][ni], 0, 0, 0);
      __syncthreads();
    }
  }

  // epilogue: out = x + relu(acc*4 + sum_c cnt_c[row]*b_c[col]);  4 = 2^6 * 2^-4
  float bcol[4][6];
#pragma unroll
  for (int ni = 0; ni < 4; ni++) {
    int gcol = n0 + ni * 16 + fr;
#pragma unroll
    for (int c = 0; c < 6; c++)
      bcol[ni][c] = (c < nch) ? args.bias[c][gcol] : 0.f;
  }
  const int rowq = (lane >> 4) * 4;
#pragma unroll
  for (int mi = 0; mi < 2; mi++) {
#pragma unroll
    for (int rI = 0; rI < 4; rI++) {
      int grow = m0 + mi * 16 + rowq + rI;
      float cv[6];
#pragma unroll
      for (int c = 0; c < 6; c++)
        cv[c] = (c < nch) ? (float)args.cnt[c][grow] : 0.f;
      size_t rowoff = (size_t)grow * DD;
#pragma unroll
      for (int ni = 0; ni < 4; ni++) {
        int gcol = n0 + ni * 16 + fr;
        float v = acc[mi][ni][rI] * 4.0f;
#pragma unroll
        for (int c = 0; c < 6; c++) v += cv[c] * bcol[ni][c];
        float outv = args.x_in[rowoff + gcol] + fmaxf(v, 0.f);
        args.x_out[rowoff + gcol] = outv;
        args.xh_out[rowoff + gcol] = (f16)outv;
      }
    }
  }
}

// ---------------- host ----------------

extern "C" void kernel_launch(void* const* d_in, const int* in_sizes, int n_in,
                              void* d_out, int out_size, void* d_ws, size_t ws_size,
                              hipStream_t stream) {
  const float* x      = (const float*)d_in[0];
  const int* edge_index = (const int*)d_in[1];
  const int* edge_attr  = (const int*)d_in[2];
  const float* W_edge = (const float*)d_in[3];
  const float* b_edge = (const float*)d_in[4];
  const float* W_hop  = (const float*)d_in[5];
  const float* b_hop  = (const float*)d_in[6];
  float* out = (float*)d_out;

  // workspace layout
  char* ws = (char*)d_ws;
  int* deg     = (int*)ws;            // N
  int* cnt     = deg + NN;            // 6N
  int* row_ptr = cnt + 6 * NN;        // N+1
  int* cursor  = row_ptr + (NN + 1);  // N
  int* records = cursor + NN;         // E
  size_t int_count = (size_t)NN + 6 * NN + (NN + 1) + NN + NE;
  const size_t ND = (size_t)NN * DD;
  f16* Wsplit = (f16*)(ws + ((int_count * 4 + 255) & ~(size_t)255));  // 24 * 65536 f16
  f16* xh = Wsplit + (size_t)24 * 65536;                              // N*D f16
  f16* aggBase = xh + ND;
  f16* agg[9];
  for (int i = 0; i < 9; i++) agg[i] = aggBase + (size_t)i * ND;
  f16** Cb = agg + 3;  // Cb[0..5]: C2_s0,C2_s1,C2_s2, C3_s0,C3_s1, C4_s0

  hipMemsetAsync(deg, 0, 7 * NN * sizeof(int), stream);
  hipMemcpyAsync(out, x, ND * sizeof(float), hipMemcpyDeviceToDevice, stream);

  k_hist<<<(NE + 255) / 256, 256, 0, stream>>>(edge_index, edge_attr, deg, cnt);
  k_scan<<<1, 1024, 0, stream>>>(deg, row_ptr, cursor);
  k_scatter<<<(NE + 255) / 256, 256, 0, stream>>>(edge_index, edge_attr, cursor, records);
  k_wsplit<<<dim3(4, 4, 24), 256, 0, stream>>>(W_edge, W_hop, Wsplit);
  k_xcast<<<ND / 1024, 256, 0, stream>>>(x, xh);

  for (int t = 0; t < TT; ++t) {
    f16* c2p = (t <= 2) ? Cb[t]     : nullptr;
    f16* c3p = (t <= 1) ? Cb[3 + t] : nullptr;
    f16* c4p = (t == 0) ? Cb[5]     : nullptr;
    k_aggregate<<<NN / 2, 256, 0, stream>>>(xh, row_ptr, records,
                                            agg[0], agg[1], agg[2], c2p, c3p, c4p);

    GemmArgs ga{};
    for (int e = 0; e < NT; ++e) {
      ga.A[e]    = agg[e];
      ga.W[e]    = Wsplit + (size_t)(t * NT + e) * 65536;
      ga.bias[e] = b_edge + (size_t)(t * NT + e) * DD;
      ga.cnt[e]  = cnt + (size_t)e * NN;
    }
    int nc = NT;
    for (int k = 2; k <= t + 1; ++k) {
      int s = t + 1 - k;
      ga.A[nc]    = (k == 2) ? Cb[s] : (k == 3) ? Cb[3 + s] : Cb[5];
      ga.W[nc]    = Wsplit + (size_t)(12 + t * 3 + (k - 2)) * 65536;
      ga.bias[nc] = b_hop + (size_t)(t * (TT - 1) + (k - 2)) * DD;
      ga.cnt[nc]  = cnt + (size_t)(3 + (k - 2)) * NN;
      nc++;
    }
    for (int c = nc; c < 6; ++c) {
      ga.A[c] = ga.A[0]; ga.W[c] = ga.W[0]; ga.bias[c] = ga.bias[0]; ga.cnt[c] = ga.cnt[0];
    }
    ga.nch = nc;
    ga.x_in = out;
    ga.x_out = out;
    ga.xh_out = xh;
    k_gemm<<<dim3(625, 4), 64, 0, stream>>>(ga);
  }
}